// Round 1
// baseline (1599.233 us; speedup 1.0000x reference)
//
#include <hip/hip_runtime.h>
#include <hip/hip_bf16.h>

#define OT_B 64
#define OT_N 512
#define OT_M 512
#define OT_ITERS 50
#define OT_STAB 1e-8f

// Kernel 1: K = exp(-C/eps) = exp(-20*C), vectorized float4 grid-stride.
__global__ __launch_bounds__(256) void ot_precompute_K(const float* __restrict__ C,
                                                       float* __restrict__ K, int total4) {
    int stride = gridDim.x * blockDim.x;
    const float4* C4 = (const float4*)C;
    float4* K4 = (float4*)K;
    for (int i = blockIdx.x * blockDim.x + threadIdx.x; i < total4; i += stride) {
        float4 c = C4[i];
        float4 k;
        k.x = expf(-20.0f * c.x);
        k.y = expf(-20.0f * c.y);
        k.z = expf(-20.0f * c.z);
        k.w = expf(-20.0f * c.w);
        K4[i] = k;
    }
}

// Kernel 2: full Sinkhorn (50 iters) + P + loss, one 1024-thread block per batch.
// PRE=true: Ksrc holds precomputed K. PRE=false: Ksrc==C, exp computed on the fly.
template <bool PRE>
__global__ __launch_bounds__(1024) void ot_sinkhorn(const float* __restrict__ Ksrc,
                                                    const float* __restrict__ Cg,
                                                    float* __restrict__ Pout,
                                                    float* __restrict__ lossOut) {
    __shared__ float u[OT_N];
    __shared__ float v[OT_M];
    __shared__ float sp[1024];

    const int b = blockIdx.x;
    const size_t batchOff = (size_t)b * OT_N * OT_M;
    const float* Kb = Ksrc + batchOff;
    const float* Cb = Cg + batchOff;
    float* Pb = Pout + batchOff;

    const int t = threadIdx.x;
    const int lane = t & 63;
    const int wave = t >> 6;
    const int j = t & (OT_M - 1);   // column owned in pass A / final pass
    const int h = t >> 9;           // which half of the row range (0/1)

    if (t < OT_N) u[t] = 1.0f / OT_N;
    __syncthreads();

    for (int it = 0; it < OT_ITERS; ++it) {
        // ---- Pass A: v_j = (1/m) / (sum_i K[i][j]*u[i] + stab) ----
        // thread t: column j, rows [h*256, h*256+256). Lane-consecutive loads.
        float acc = 0.0f;
        const float* colp = Kb + (size_t)(h * (OT_N / 2)) * OT_M + j;
        const float* ures = &u[h * (OT_N / 2)];
        #pragma unroll 16
        for (int i = 0; i < OT_N / 2; ++i) {
            float kv = colp[(size_t)i * OT_M];
            if (!PRE) kv = expf(-20.0f * kv);
            acc += kv * ures[i];
        }
        sp[t] = acc;
        __syncthreads();
        if (t < OT_M) v[t] = (1.0f / OT_M) / (sp[t] + sp[t + OT_M] + OT_STAB);
        __syncthreads();

        // ---- Pass B: u_i = (1/n) / (sum_j K[i][j]*v[j] + stab) ----
        // wave handles rows r and r+16 concurrently (MLP), lane-coalesced.
        for (int r = wave; r < OT_N; r += 32) {
            const float* row0 = Kb + (size_t)r * OT_M;
            const float* row1 = Kb + (size_t)(r + 16) * OT_M;
            float s0 = 0.0f, s1 = 0.0f;
            #pragma unroll
            for (int k = 0; k < OT_M / 64; ++k) {
                float a0 = row0[lane + 64 * k];
                float a1 = row1[lane + 64 * k];
                if (!PRE) { a0 = expf(-20.0f * a0); a1 = expf(-20.0f * a1); }
                float vv = v[lane + 64 * k];
                s0 += a0 * vv;
                s1 += a1 * vv;
            }
            #pragma unroll
            for (int off = 32; off >= 1; off >>= 1) {
                s0 += __shfl_xor(s0, off);
                s1 += __shfl_xor(s1, off);
            }
            if (lane == 0) {
                u[r]      = (1.0f / OT_N) / (s0 + OT_STAB);
                u[r + 16] = (1.0f / OT_N) / (s1 + OT_STAB);
            }
        }
        __syncthreads();
    }

    // ---- Final pass: P = u_i*K_ij*v_j, loss = sum(P*C) ----
    float lacc = 0.0f;
    #pragma unroll 4
    for (int base = 0; base < OT_N; base += 2) {
        int i = base + h;
        size_t off = (size_t)i * OT_M + j;
        float kv = Kb[off];
        if (!PRE) kv = expf(-20.0f * kv);
        float p = u[i] * kv * v[j];
        Pb[off] = p;
        lacc += p * Cb[off];
    }
    sp[t] = lacc;
    __syncthreads();
    for (int s = 512; s >= 1; s >>= 1) {
        if (t < s) sp[t] += sp[t + s];
        __syncthreads();
    }
    if (t == 0) lossOut[b] = sp[0];
}

extern "C" void kernel_launch(void* const* d_in, const int* in_sizes, int n_in,
                              void* d_out, int out_size, void* d_ws, size_t ws_size,
                              hipStream_t stream) {
    const float* C = (const float*)d_in[0];
    float* P = (float*)d_out;
    float* loss = (float*)d_out + (size_t)OT_B * OT_N * OT_M;

    const size_t kbytes = (size_t)OT_B * OT_N * OT_M * sizeof(float);
    if (ws_size >= kbytes) {
        float* K = (float*)d_ws;
        const int total4 = OT_B * OT_N * OT_M / 4;
        ot_precompute_K<<<2048, 256, 0, stream>>>(C, K, total4);
        ot_sinkhorn<true><<<OT_B, 1024, 0, stream>>>(K, C, P, loss);
    } else {
        ot_sinkhorn<false><<<OT_B, 1024, 0, stream>>>(C, C, P, loss);
    }
}